// Round 1
// baseline (416.792 us; speedup 1.0000x reference)
//
#include <hip/hip_runtime.h>

// MHA: B=2, S=2048, D=1024, H=16, hd=64. fp32 in/out, bf16 MFMA internally.
// R0: correctness-first full-MFMA pipeline (cast -> gemm_qkv -> flash attn -> gemm_out).

typedef __bf16 bf16;
typedef __bf16 bf16x4 __attribute__((ext_vector_type(4)));
typedef __bf16 bf16x8 __attribute__((ext_vector_type(8)));
typedef float f32x4 __attribute__((ext_vector_type(4)));

#define MFMA(a, b, c) __builtin_amdgcn_mfma_f32_16x16x32_bf16((a), (b), (c), 0, 0, 0)

// ---------------- cast fp32 -> bf16, 4 elems/thread ----------------
__global__ void cast4_kernel(const float* __restrict__ in, bf16* __restrict__ out, int n4) {
    int i = blockIdx.x * blockDim.x + threadIdx.x;
    if (i < n4) {
        float4 v = ((const float4*)in)[i];
        bf16x4 o = {(bf16)v.x, (bf16)v.y, (bf16)v.z, (bf16)v.w};
        ((bf16x4*)out)[i] = o;
    }
}

// ---------------- transpose + cast: in [R,C] fp32 -> out [C,R] bf16 ----------------
__global__ void transpose_cast_kernel(const float* __restrict__ in, bf16* __restrict__ out,
                                      int R, int C) {
    __shared__ float tile[32][33];
    int bx = blockIdx.x * 32;  // col base (C)
    int by = blockIdx.y * 32;  // row base (R)
    int tx = threadIdx.x, ty = threadIdx.y;  // (32,8)
    for (int i = 0; i < 32; i += 8)
        tile[ty + i][tx] = in[(size_t)(by + ty + i) * C + bx + tx];
    __syncthreads();
    for (int i = 0; i < 32; i += 8)
        out[(size_t)(bx + ty + i) * R + by + tx] = (bf16)tile[tx][ty + i];
}

// ---------------- GEMM1: X[4096,1024] @ Wqkv -> scatter Q,K,VT (bf16) ----------------
// A row-major [M,K] bf16; BT row-major [N,K] bf16 (pre-transposed weight).
// Block tile 128x128, 4 waves each 64x64 (4x4 of 16x16 MFMA), BK=32.
#define LDK 40  // padded LDS row stride (elements) to spread banks

__global__ __launch_bounds__(256) void gemm_qkv_kernel(
    const bf16* __restrict__ A, const bf16* __restrict__ BT,
    const float* __restrict__ bias,
    bf16* __restrict__ Q, bf16* __restrict__ K, bf16* __restrict__ VT) {
    const int KDIM = 1024;
    __shared__ bf16 As[128 * LDK];
    __shared__ bf16 Bs[128 * LDK];
    int bm = blockIdx.x, bn = blockIdx.y;
    int t = threadIdx.x;
    int w = t >> 6, lane = t & 63, g = lane >> 4, l16 = lane & 15;
    int wm = (w >> 1) * 64, wn = (w & 1) * 64;
    f32x4 acc[4][4] = {};
    const bf16* Ablk = A + (size_t)(bm * 128) * KDIM;
    const bf16* Bblk = BT + (size_t)(bn * 128) * KDIM;

    for (int kb = 0; kb < KDIM; kb += 32) {
        __syncthreads();  // WAR: previous frag reads done
        for (int c = t; c < 512; c += 256) {
            int row = c >> 2, cc = c & 3;
            *(bf16x8*)(&As[row * LDK + cc * 8]) =
                *(const bf16x8*)(&Ablk[(size_t)row * KDIM + kb + cc * 8]);
            *(bf16x8*)(&Bs[row * LDK + cc * 8]) =
                *(const bf16x8*)(&Bblk[(size_t)row * KDIM + kb + cc * 8]);
        }
        __syncthreads();
        bf16x8 af[4], bfr[4];
        for (int mi = 0; mi < 4; mi++)
            af[mi] = *(const bf16x8*)(&As[(wm + mi * 16 + l16) * LDK + g * 8]);
        for (int ni = 0; ni < 4; ni++)
            bfr[ni] = *(const bf16x8*)(&Bs[(wn + ni * 16 + l16) * LDK + g * 8]);
        for (int mi = 0; mi < 4; mi++)
            for (int ni = 0; ni < 4; ni++)
                acc[mi][ni] = MFMA(af[mi], bfr[ni], acc[mi][ni]);
    }

    // epilogue: scatter to Q [bh,s,d], K [bh,s,d], VT [bh,d,s]
    for (int mi = 0; mi < 4; mi++) {
        for (int ni = 0; ni < 4; ni++) {
            int col = bn * 128 + wn + ni * 16 + l16;  // 0..3071
            float bv = bias[col];
            int h = col / 192, tt = col % 192;
            for (int r = 0; r < 4; r++) {
                int row = bm * 128 + wm + mi * 16 + g * 4 + r;  // 0..4095
                float v = acc[mi][ni][r] + bv;
                int b = row >> 11, s = row & 2047;
                size_t bh = (size_t)(b * 16 + h);
                if (tt < 64)
                    Q[(bh * 2048 + s) * 64 + tt] = (bf16)v;
                else if (tt < 128)
                    K[(bh * 2048 + s) * 64 + (tt - 64)] = (bf16)v;
                else
                    VT[(bh * 64 + (tt - 128)) * 2048 + s] = (bf16)v;
            }
        }
    }
}

// ---------------- flash attention ----------------
// grid = 1024 (32 bh * 32 q-tiles of 64), block = 256 (4 waves x 16 q-rows).
__global__ __launch_bounds__(256) void attn_kernel(
    const bf16* __restrict__ Q, const bf16* __restrict__ K,
    const bf16* __restrict__ VT, const float* __restrict__ mask,
    bf16* __restrict__ vals) {
    int blk = blockIdx.x;
    int qt = blk & 31, bh = blk >> 5;
    int w = threadIdx.x >> 6, lane = threadIdx.x & 63, g = lane >> 4, l16 = lane & 15;
    int qbase = qt * 64 + w * 16;
    const bf16* Qp = Q + (size_t)bh * 2048 * 64;
    const bf16* Kp = K + (size_t)bh * 2048 * 64;
    const bf16* Vp = VT + (size_t)bh * 64 * 2048;

    // Q fragments for this wave's 16 rows (A-layout: m=l16, k=g*8+j)
    bf16x8 q0 = *(const bf16x8*)(&Qp[(size_t)(qbase + l16) * 64 + g * 8]);
    bf16x8 q1 = *(const bf16x8*)(&Qp[(size_t)(qbase + l16) * 64 + 32 + g * 8]);

    f32x4 o[4] = {};
    float m[4], l[4];
    for (int r = 0; r < 4; r++) { m[r] = -1e30f; l[r] = 0.f; }

    __shared__ bf16 Plds[4][16 * 32];

    for (int kb = 0; kb < 2048; kb += 32) {
        // scores: two 16-col subtiles
        f32x4 s0 = {}, s1 = {};
        {
            bf16x8 k0 = *(const bf16x8*)(&Kp[(size_t)(kb + l16) * 64 + g * 8]);
            bf16x8 k1 = *(const bf16x8*)(&Kp[(size_t)(kb + l16) * 64 + 32 + g * 8]);
            s0 = MFMA(q0, k0, s0);
            s0 = MFMA(q1, k1, s0);
            bf16x8 k2 = *(const bf16x8*)(&Kp[(size_t)(kb + 16 + l16) * 64 + g * 8]);
            bf16x8 k3 = *(const bf16x8*)(&Kp[(size_t)(kb + 16 + l16) * 64 + 32 + g * 8]);
            s1 = MFMA(q0, k2, s1);
            s1 = MFMA(q1, k3, s1);
        }
        // scale + mask (C-layout: row=g*4+r, col=l16 / l16+16)
        float sc[8];
        for (int r = 0; r < 4; r++) {
            int sq = qbase + g * 4 + r;
            sc[r]     = s0[r] * 0.125f + mask[(size_t)sq * 2048 + kb + l16];
            sc[4 + r] = s1[r] * 0.125f + mask[(size_t)sq * 2048 + kb + 16 + l16];
        }
        // online softmax update
        float alpha[4], pr[8];
        for (int r = 0; r < 4; r++) {
            float v = fmaxf(sc[r], sc[4 + r]);
            for (int off = 8; off; off >>= 1) v = fmaxf(v, __shfl_xor(v, off, 16));
            float mn = fmaxf(m[r], v);
            alpha[r] = __expf(m[r] - mn);
            m[r] = mn;
        }
        for (int r = 0; r < 4; r++) {
            pr[r] = __expf(sc[r] - m[r]);
            pr[4 + r] = __expf(sc[4 + r] - m[r]);
            float v = pr[r] + pr[4 + r];
            for (int off = 8; off; off >>= 1) v += __shfl_xor(v, off, 16);
            l[r] = l[r] * alpha[r] + v;
            for (int nc = 0; nc < 4; nc++) o[nc][r] *= alpha[r];
        }
        // P -> LDS (C-layout write), read back in A-layout
        for (int r = 0; r < 4; r++) {
            Plds[w][(g * 4 + r) * 32 + l16] = (bf16)pr[r];
            Plds[w][(g * 4 + r) * 32 + 16 + l16] = (bf16)pr[4 + r];
        }
        __syncthreads();
        bf16x8 pa = *(const bf16x8*)(&Plds[w][l16 * 32 + g * 8]);
        for (int nc = 0; nc < 4; nc++) {
            bf16x8 vf = *(const bf16x8*)(&Vp[(size_t)(nc * 16 + l16) * 2048 + kb + g * 8]);
            o[nc] = MFMA(pa, vf, o[nc]);
        }
        __syncthreads();  // WAR before next iter's P write
    }

    // normalize + store vals [4096,1024] bf16
    int b = bh >> 4, h = bh & 15;
    for (int nc = 0; nc < 4; nc++) {
        for (int r = 0; r < 4; r++) {
            int row = b * 2048 + qbase + g * 4 + r;
            int col = h * 64 + nc * 16 + l16;
            vals[(size_t)row * 1024 + col] = (bf16)(o[nc][r] / l[r]);
        }
    }
}

// ---------------- GEMM3: vals[4096,1024] @ Wout -> out fp32 ----------------
__global__ __launch_bounds__(256) void gemm_out_kernel(
    const bf16* __restrict__ A, const bf16* __restrict__ BT,
    const float* __restrict__ bias, float* __restrict__ out) {
    const int KDIM = 1024;
    __shared__ bf16 As[128 * LDK];
    __shared__ bf16 Bs[128 * LDK];
    int bm = blockIdx.x, bn = blockIdx.y;
    int t = threadIdx.x;
    int w = t >> 6, lane = t & 63, g = lane >> 4, l16 = lane & 15;
    int wm = (w >> 1) * 64, wn = (w & 1) * 64;
    f32x4 acc[4][4] = {};
    const bf16* Ablk = A + (size_t)(bm * 128) * KDIM;
    const bf16* Bblk = BT + (size_t)(bn * 128) * KDIM;

    for (int kb = 0; kb < KDIM; kb += 32) {
        __syncthreads();
        for (int c = t; c < 512; c += 256) {
            int row = c >> 2, cc = c & 3;
            *(bf16x8*)(&As[row * LDK + cc * 8]) =
                *(const bf16x8*)(&Ablk[(size_t)row * KDIM + kb + cc * 8]);
            *(bf16x8*)(&Bs[row * LDK + cc * 8]) =
                *(const bf16x8*)(&Bblk[(size_t)row * KDIM + kb + cc * 8]);
        }
        __syncthreads();
        bf16x8 af[4], bfr[4];
        for (int mi = 0; mi < 4; mi++)
            af[mi] = *(const bf16x8*)(&As[(wm + mi * 16 + l16) * LDK + g * 8]);
        for (int ni = 0; ni < 4; ni++)
            bfr[ni] = *(const bf16x8*)(&Bs[(wn + ni * 16 + l16) * LDK + g * 8]);
        for (int mi = 0; mi < 4; mi++)
            for (int ni = 0; ni < 4; ni++)
                acc[mi][ni] = MFMA(af[mi], bfr[ni], acc[mi][ni]);
    }

    for (int mi = 0; mi < 4; mi++) {
        for (int ni = 0; ni < 4; ni++) {
            int col = bn * 128 + wn + ni * 16 + l16;
            float bv = bias[col];
            for (int r = 0; r < 4; r++) {
                int row = bm * 128 + wm + mi * 16 + g * 4 + r;
                out[(size_t)row * 1024 + col] = acc[mi][ni][r] + bv;
            }
        }
    }
}

// ---------------- launch ----------------
extern "C" void kernel_launch(void* const* d_in, const int* in_sizes, int n_in,
                              void* d_out, int out_size, void* d_ws, size_t ws_size,
                              hipStream_t stream) {
    const float* x     = (const float*)d_in[0];  // [2,2048,1024]
    const float* mask  = (const float*)d_in[1];  // [2048,2048]
    const float* w_qkv = (const float*)d_in[2];  // [1024,3072]
    const float* b_qkv = (const float*)d_in[3];  // [3072]
    const float* w_out = (const float*)d_in[4];  // [1024,1024]
    const float* b_out = (const float*)d_in[5];  // [1024]
    float* out = (float*)d_out;

    char* ws = (char*)d_ws;
    size_t off = 0;
    bf16* xb    = (bf16*)(ws + off); off += (size_t)4096 * 1024 * 2;
    bf16* wqkvT = (bf16*)(ws + off); off += (size_t)3072 * 1024 * 2;
    bf16* woutT = (bf16*)(ws + off); off += (size_t)1024 * 1024 * 2;
    bf16* Qa    = (bf16*)(ws + off); off += (size_t)32 * 2048 * 64 * 2;
    bf16* Ka    = (bf16*)(ws + off); off += (size_t)32 * 2048 * 64 * 2;
    bf16* VTa   = (bf16*)(ws + off); off += (size_t)32 * 64 * 2048 * 2;
    bf16* vals  = (bf16*)(ws + off); off += (size_t)4096 * 1024 * 2;

    // cast x -> bf16 (4096*1024 elems, 4/thread)
    cast4_kernel<<<4096, 256, 0, stream>>>(x, xb, 4096 * 1024 / 4);
    // transpose+cast weights
    transpose_cast_kernel<<<dim3(96, 32), dim3(32, 8), 0, stream>>>(w_qkv, wqkvT, 1024, 3072);
    transpose_cast_kernel<<<dim3(32, 32), dim3(32, 8), 0, stream>>>(w_out, woutT, 1024, 1024);
    // QKV projection + scatter
    gemm_qkv_kernel<<<dim3(32, 24), 256, 0, stream>>>(xb, wqkvT, b_qkv, Qa, Ka, VTa);
    // flash attention
    attn_kernel<<<1024, 256, 0, stream>>>(Qa, Ka, VTa, mask, vals);
    // output projection
    gemm_out_kernel<<<dim3(32, 8), 256, 0, stream>>>(vals, woutT, b_out, out);
}